// Round 1
// baseline (9.577 us; speedup 1.0000x reference)
//
#include <hip/hip_runtime.h>

// reference(x, y) = mean(|hist(x) - hist(x)|) == 0.0 exactly, for all inputs.
// (y is unused in the reference; the histogram is compared against itself.)
// The only observable output is a single float32 zero.
__global__ void ColorHistCriterion_56521769615944_kernel(float* out) {
    out[0] = 0.0f;
}

extern "C" void kernel_launch(void* const* d_in, const int* in_sizes, int n_in,
                              void* d_out, int out_size, void* d_ws, size_t ws_size,
                              hipStream_t stream) {
    (void)d_in; (void)in_sizes; (void)n_in; (void)out_size; (void)d_ws; (void)ws_size;
    float* out = (float*)d_out;
    ColorHistCriterion_56521769615944_kernel<<<1, 1, 0, stream>>>(out);
}